// Round 5
// baseline (613.793 us; speedup 1.0000x reference)
//
#include <hip/hip_runtime.h>
#include <math.h>

#define DD 64
#define BIGF 1.0e9f

// uniform-lane broadcast via v_readlane (no DS pipe)
__device__ __forceinline__ float bcastf(float x, int lane) {
    return __builtin_bit_cast(float, __builtin_amdgcn_readlane(__builtin_bit_cast(int, x), lane));
}
__device__ __forceinline__ int bcasti(int x, int lane) {
    return __builtin_amdgcn_readlane(x, lane);
}

// full-wave64 min via DPP (pure VALU): row_shr 1/2/4/8 + row_bcast15/31.
__device__ __forceinline__ float wave_min64(float x) {
#define STEPD(ctrl)                                                                \
    {                                                                              \
        int _t = __builtin_amdgcn_update_dpp(__builtin_bit_cast(int, x),           \
                                             __builtin_bit_cast(int, x),           \
                                             ctrl, 0xF, 0xF, false);               \
        x = fminf(x, __builtin_bit_cast(float, _t));                               \
    }
    STEPD(0x111)  // row_shr:1
    STEPD(0x112)  // row_shr:2
    STEPD(0x114)  // row_shr:4
    STEPD(0x118)  // row_shr:8
    STEPD(0x142)  // row_bcast:15
    STEPD(0x143)  // row_bcast:31
#undef STEPD
    return bcastf(x, 63);
}

// ---- Stage: cost = -(gamma + gumbel), gumbel = -log(-log(clip(u))) ----
// logs in double, rounded to f32 (bit-matched the reference in r1..r4).
__global__ __launch_bounds__(256) void stage_kernel(
    const float* __restrict__ gamma,
    const float* __restrict__ uin,
    float* __restrict__ cost,
    int total4)
{
    int idx = blockIdx.x * blockDim.x + threadIdx.x;
    if (idx >= total4) return;
    const float lo = 1e-20f;
    const float hi = (float)(1.0 - 1e-7);

    float4 u4 = ((const float4*)uin)[idx];
    int e = idx << 2;
    const float4 g4 = *(const float4*)(gamma + (e & (DD * DD - 1)));

    float uu[4] = {u4.x, u4.y, u4.z, u4.w};
    float gg[4] = {g4.x, g4.y, g4.z, g4.w};
    float rr[4];
#pragma unroll
    for (int k = 0; k < 4; ++k) {
        float x = fminf(fmaxf(uu[k], lo), hi);
        float inner = (float)log((double)x);
        float outer = (float)log((double)(-inner));
        float sc = gg[k] + (-outer);
        rr[k] = -sc;
    }
    float4 r4 = {rr[0], rr[1], rr[2], rr[3]};
    ((float4*)cost)[idx] = r4;
}

// One search iteration for sample S. All ops are selects/cross-lane — no
// branches, so STEP(A);STEP(B) share one basic block and their dependency
// chains interleave. Bit-exact f32 replication of the reference ops.
#define STEP(S) do {                                                         \
    float cur = (c##S - u##S) - v##S;                                        \
    bool bett = (!used##S) && (cur < minv##S);                               \
    minv##S = bett ? cur : minv##S;                                          \
    way##S  = bett ? j0##S : way##S;                                         \
    float masked = used##S ? BIGF : minv##S;                                 \
    float delta = wave_min64(masked);                                        \
    unsigned long long tie = __ballot(masked == delta);                      \
    int j1 = (int)__ffsll(tie);                                              \
    j1 = __builtin_amdgcn_readfirstlane(j1);                                 \
    pj1##S = bcasti(p##S, j1 - 1);                                           \
    int nrow = (pj1##S != 0 ? pj1##S : 1) - 1;                               \
    float cn = cb##S[nrow * DD + l];                                         \
    float un = bcastf(ud##S, nrow);                                          \
    float du = used##S ? delta : 0.0f;                                       \
    float di = inTree##S ? delta : 0.0f;                                     \
    ud##S += di;                                                             \
    v##S  -= du;                                                             \
    minv##S -= (delta - du);                                                 \
    used##S   = used##S   || (l == (j1 - 1));                                \
    inTree##S = inTree##S || (l == (pj1##S - 1));                            \
    j0##S = j1;                                                              \
    c##S = cn; u##S = un;                                                    \
} while (0)

// Augment along way[] chain, then advance to next row (or mark done).
#define AUGNEXT(S) do {                                                      \
    int j0 = j0##S;                                                          \
    while (j0 != 0) {                                                        \
        int jn = bcasti(way##S, j0 - 1);                                     \
        int pn = (jn == 0) ? (i##S + 1) : bcasti(p##S, jn - 1);              \
        if (l == (j0 - 1)) p##S = pn;                                        \
        j0 = jn;                                                             \
    }                                                                        \
    ++i##S;                                                                  \
    if (i##S >= DD) { done##S = true; }                                      \
    else {                                                                   \
        minv##S = BIGF; way##S = 0; used##S = false; inTree##S = (l == i##S);\
        j0##S = 0;                                                           \
        c##S = cb##S[i##S * DD + l];                                         \
        u##S = bcastf(ud##S, i##S);                                          \
    }                                                                        \
} while (0)

// ---- LAP: one wave per block, TWO samples per wave (independent progress).
// Lane l owns column j=l+1 state (v,minv,way,p,used) and row r=l+1 dual u,
// duplicated for samples A and B. A finished sample spins harmlessly (its p
// is a complete matching, so pj1 != 0 always; p is never written after done).
__global__ __launch_bounds__(64, 4) void lap64_kernel(float* __restrict__ cost, int nsamp)
{
    const int l = threadIdx.x & 63;
    const int w = blockIdx.x;
    const int bA = 2 * w;
    const int bB = 2 * w + 1;
    if (bA >= nsamp) return;
    const bool haveB = (bB < nsamp);
    float* cbA = cost + (size_t)bA * (DD * DD);
    float* cbB = cost + (size_t)(haveB ? bB : bA) * (DD * DD);

    float vA = 0.f, udA = 0.f, minvA = BIGF, cA = cbA[l], uA = 0.f;
    int   pA = 0, wayA = 0, j0A = 0, pj1A = 1, iA = 0;
    bool  usedA = false, inTreeA = (l == 0), doneA = false;

    float vB = 0.f, udB = 0.f, minvB = BIGF, cB = cbB[l], uB = 0.f;
    int   pB = 0, wayB = 0, j0B = 0, pj1B = 1, iB = 0;
    bool  usedB = false, inTreeB = (l == 0), doneB = !haveB;

    for (int g = 0; g < 20000; ++g) {
        if (doneA && doneB) break;
        STEP(A);
        STEP(B);
        if (!doneA && pj1A == 0) AUGNEXT(A);
        if (!doneB && pj1B == 0) AUGNEXT(B);
    }

    // ---- overwrite cost regions with one-hot permutations ----
    {
        const int prA = pA - 1;
        for (int r = 0; r < DD; ++r) cbA[r * DD + l] = (prA == r) ? 1.0f : 0.0f;
    }
    if (haveB) {
        const int prB = pB - 1;
        for (int r = 0; r < DD; ++r) cbB[r * DD + l] = (prB == r) ? 1.0f : 0.0f;
    }
}

extern "C" void kernel_launch(void* const* d_in, const int* in_sizes, int n_in,
                              void* d_out, int out_size, void* d_ws, size_t ws_size,
                              hipStream_t stream) {
    const float* gamma = (const float*)d_in[0];
    const float* u     = (const float*)d_in[1];
    float* out = (float*)d_out;
    const int nsamp = in_sizes[1] / (DD * DD);
    const int total4 = nsamp * DD * DD / 4;

    stage_kernel<<<dim3((total4 + 255) / 256), dim3(256), 0, stream>>>(gamma, u, out, total4);
    const int nwave = (nsamp + 1) / 2;
    lap64_kernel<<<dim3(nwave), dim3(64), 0, stream>>>(out, nsamp);
}

// Round 6
// 468.133 us; speedup vs baseline: 1.3112x; 1.3112x over previous
//
#include <hip/hip_runtime.h>
#include <math.h>

#define DD 64
#define BIGF 1.0e9f

// uniform-lane broadcast via v_readlane (no DS pipe)
__device__ __forceinline__ float bcastf(float x, int lane) {
    return __builtin_bit_cast(float, __builtin_amdgcn_readlane(__builtin_bit_cast(int, x), lane));
}
__device__ __forceinline__ int bcasti(int x, int lane) {
    return __builtin_amdgcn_readlane(x, lane);
}

// full-wave64 min via DPP (pure VALU): row_shr 1/2/4/8 + row_bcast15/31.
__device__ __forceinline__ float wave_min64(float x) {
#define STEPD(ctrl)                                                                \
    {                                                                              \
        int _t = __builtin_amdgcn_update_dpp(__builtin_bit_cast(int, x),           \
                                             __builtin_bit_cast(int, x),           \
                                             ctrl, 0xF, 0xF, false);               \
        x = fminf(x, __builtin_bit_cast(float, _t));                               \
    }
    STEPD(0x111)  // row_shr:1
    STEPD(0x112)  // row_shr:2
    STEPD(0x114)  // row_shr:4
    STEPD(0x118)  // row_shr:8
    STEPD(0x142)  // row_bcast:15
    STEPD(0x143)  // row_bcast:31
#undef STEPD
    return bcastf(x, 63);
}

// ---- Stage: cost = -(gamma + gumbel), gumbel = -log(-log(clip(u))) ----
// logs in double, rounded to f32 (bit-matched the reference in r1..r5).
__global__ __launch_bounds__(256) void stage_kernel(
    const float* __restrict__ gamma,
    const float* __restrict__ uin,
    float* __restrict__ cost,
    int total4)
{
    int idx = blockIdx.x * blockDim.x + threadIdx.x;
    if (idx >= total4) return;
    const float lo = 1e-20f;
    const float hi = (float)(1.0 - 1e-7);

    float4 u4 = ((const float4*)uin)[idx];
    int e = idx << 2;
    const float4 g4 = *(const float4*)(gamma + (e & (DD * DD - 1)));

    float uu[4] = {u4.x, u4.y, u4.z, u4.w};
    float gg[4] = {g4.x, g4.y, g4.z, g4.w};
    float rr[4];
#pragma unroll
    for (int k = 0; k < 4; ++k) {
        float x = fminf(fmaxf(uu[k], lo), hi);
        float inner = (float)log((double)x);
        float outer = (float)log((double)(-inner));
        float sc = gg[k] + (-outer);
        rr[k] = -sc;
    }
    float4 r4 = {rr[0], rr[1], rr[2], rr[3]};
    ((float4*)cost)[idx] = r4;
}

// ---- LAP: 128-thread blocks = 2 independent waves, 1 sample each. ----
// Lane l owns column j=l+1 state (v,minv,way,p,used) and row r=l+1 dual u.
// Bit-exact f32 replication of the reference Jonker-Volgenant trajectory:
//  - minv holds BIG for used lanes (their reference minv is provably dead),
//    so minv IS the masked argmin array (saves one select per iteration).
//  - minv -= (delta - du): used lanes subtract exactly 0 (BIG preserved),
//    unused subtract delta — exact same f32 result as the reference.
//  - u[i0] prefetch reads lane pj1-1 BEFORE ud += di: that lane is not yet
//    inTree, so its ud is unchanged by this iteration's update.
// Each wave overwrites its sample's cost region with the one-hot output.
__global__ __launch_bounds__(128) void lap64_kernel(float* __restrict__ cost, int nsamp)
{
    const int l = threadIdx.x & 63;
    const int b = blockIdx.x * 2 + (threadIdx.x >> 6);
    if (b >= nsamp) return;
    float* cb = cost + (size_t)b * (DD * DD);

    float v  = 0.0f;  // v[l+1]
    float ud = 0.0f;  // u[l+1]
    int   p  = 0;     // p[l+1] (1-based row matched to column l+1; 0 = none)

    for (int i = 0; i < DD; ++i) {
        float minv = BIGF;
        int   way  = 0;
        bool  used = false;
        bool  inTree = (l == i);      // row i+1 enters tree via virtual col 0
        int   j0 = 0;
        float c    = cb[i * DD + l];  // row i0-1 = i
        float u_i0 = bcastf(ud, i);   // u[i+1]

        for (int it = 0; it <= DD; ++it) {
            float cur = (c - u_i0) - v;            // ((cost - u) - v), as reference
            bool bett = (!used) && (cur < minv);
            minv = bett ? cur : minv;              // used lanes stay at BIG
            way  = bett ? j0  : way;

            float delta = wave_min64(minv);        // minv is already masked
            unsigned long long tie = __ballot(minv == delta);
            int j1 = __ffsll(tie);                 // first-index tie-break
            j1 = __builtin_amdgcn_readfirstlane(j1);
            int pj1 = bcasti(p, j1 - 1);

            // prefetch next row + next u[i0] (lane pj1-1 not yet inTree)
            if (pj1 != 0) {
                c    = cb[(pj1 - 1) * DD + l];
                u_i0 = bcastf(ud, pj1 - 1);
            }

            // dual updates (reference's where()-updates, exact)
            float du = used ? delta : 0.0f;
            float di = inTree ? delta : 0.0f;
            ud += di;
            v  -= du;
            minv -= (delta - du);                  // used: -0 (BIG kept); unused: -delta

            bool isj1 = (l == (j1 - 1));
            used = used || isj1;
            minv = isj1 ? BIGF : minv;             // inject BIG for newly-used lane
            j0 = j1;
            if (pj1 == 0) break;
            inTree = inTree || (l == (pj1 - 1));
        }

        // ---- augment along way[] chain ----
        while (j0 != 0) {
            int jn = bcasti(way, j0 - 1);
            int pn = (jn == 0) ? (i + 1) : bcasti(p, jn - 1);
            if (l == (j0 - 1)) p = pn;
            j0 = jn;
        }
    }

    // ---- overwrite cost region with one-hot permutation: out[b][p-1][l] = 1 ----
    const int prow = p - 1;
    for (int r = 0; r < DD; ++r) {
        cb[r * DD + l] = (prow == r) ? 1.0f : 0.0f;
    }
}

extern "C" void kernel_launch(void* const* d_in, const int* in_sizes, int n_in,
                              void* d_out, int out_size, void* d_ws, size_t ws_size,
                              hipStream_t stream) {
    const float* gamma = (const float*)d_in[0];
    const float* u     = (const float*)d_in[1];
    float* out = (float*)d_out;
    const int nsamp = in_sizes[1] / (DD * DD);
    const int total4 = nsamp * DD * DD / 4;

    stage_kernel<<<dim3((total4 + 255) / 256), dim3(256), 0, stream>>>(gamma, u, out, total4);
    lap64_kernel<<<dim3((nsamp + 1) / 2), dim3(128), 0, stream>>>(out, nsamp);
}

// Round 7
// 466.165 us; speedup vs baseline: 1.3167x; 1.0042x over previous
//
#include <hip/hip_runtime.h>
#include <math.h>

#define DD 64
#define BIGF 1.0e9f

// uniform-lane broadcast via v_readlane (no DS pipe)
__device__ __forceinline__ float bcastf(float x, int lane) {
    return __builtin_bit_cast(float, __builtin_amdgcn_readlane(__builtin_bit_cast(int, x), lane));
}
__device__ __forceinline__ int bcasti(int x, int lane) {
    return __builtin_amdgcn_readlane(x, lane);
}

// full-wave64 min via DPP (pure VALU): row_shr 1/2/4/8 + row_bcast15/31.
__device__ __forceinline__ float wave_min64(float x) {
#define STEPD(ctrl)                                                                \
    {                                                                              \
        int _t = __builtin_amdgcn_update_dpp(__builtin_bit_cast(int, x),           \
                                             __builtin_bit_cast(int, x),           \
                                             ctrl, 0xF, 0xF, false);               \
        x = fminf(x, __builtin_bit_cast(float, _t));                               \
    }
    STEPD(0x111)  // row_shr:1
    STEPD(0x112)  // row_shr:2
    STEPD(0x114)  // row_shr:4
    STEPD(0x118)  // row_shr:8
    STEPD(0x142)  // row_bcast:15
    STEPD(0x143)  // row_bcast:31
#undef STEPD
    return bcastf(x, 63);
}

// ---- Stage: cost = -(gamma + gumbel), gumbel = -log(-log(clip(u))) ----
// logs in double, rounded to f32 (bit-matched the reference in r1..r6).
__global__ __launch_bounds__(256) void stage_kernel(
    const float* __restrict__ gamma,
    const float* __restrict__ uin,
    float* __restrict__ cost,
    int total4)
{
    int idx = blockIdx.x * blockDim.x + threadIdx.x;
    if (idx >= total4) return;
    const float lo = 1e-20f;
    const float hi = (float)(1.0 - 1e-7);

    float4 u4 = ((const float4*)uin)[idx];
    int e = idx << 2;
    const float4 g4 = *(const float4*)(gamma + (e & (DD * DD - 1)));

    float uu[4] = {u4.x, u4.y, u4.z, u4.w};
    float gg[4] = {g4.x, g4.y, g4.z, g4.w};
    float rr[4];
#pragma unroll
    for (int k = 0; k < 4; ++k) {
        float x = fminf(fmaxf(uu[k], lo), hi);
        float inner = (float)log((double)x);
        float outer = (float)log((double)(-inner));
        float sc = gg[k] + (-outer);
        rr[k] = -sc;
    }
    float4 r4 = {rr[0], rr[1], rr[2], rr[3]};
    ((float4*)cost)[idx] = r4;
}

// ---- LAP: 256-thread blocks = 4 independent waves, 1 sample each. ----
// __launch_bounds__(256, 8): force VGPR <= 64 so 8 waves/SIMD are resident
// (r3/r4/r6 all capped at 4 waves/SIMD = 53% occupancy: compiler allocated
// ~128 VGPRs with no occupancy target; live state is ~25 regs).
// Lane l owns column j=l+1 state (v,minv,way,p,used) and row r=l+1 dual u.
// Bit-exact f32 replication of the reference Jonker-Volgenant trajectory:
//  - minv holds BIG for used lanes (their reference minv is provably dead),
//    so minv IS the masked argmin array.
//  - minv -= (delta - du): used lanes subtract exactly 0 (BIG preserved).
//  - u[i0] prefetch reads lane pj1-1 BEFORE ud += di (not yet inTree).
// Each wave overwrites its sample's cost region with the one-hot output.
__global__ __launch_bounds__(256, 8) void lap64_kernel(float* __restrict__ cost, int nsamp)
{
    const int l = threadIdx.x & 63;
    const int b = blockIdx.x * 4 + (threadIdx.x >> 6);
    if (b >= nsamp) return;
    float* cb = cost + (size_t)b * (DD * DD);

    float v  = 0.0f;  // v[l+1]
    float ud = 0.0f;  // u[l+1]
    int   p  = 0;     // p[l+1] (1-based row matched to column l+1; 0 = none)

    for (int i = 0; i < DD; ++i) {
        float minv = BIGF;
        int   way  = 0;
        bool  used = false;
        bool  inTree = (l == i);      // row i+1 enters tree via virtual col 0
        int   j0 = 0;
        float c    = cb[i * DD + l];  // row i0-1 = i
        float u_i0 = bcastf(ud, i);   // u[i+1]

        for (int it = 0; it <= DD; ++it) {
            float cur = (c - u_i0) - v;            // ((cost - u) - v), as reference
            bool bett = (!used) && (cur < minv);
            minv = bett ? cur : minv;              // used lanes stay at BIG
            way  = bett ? j0  : way;

            float delta = wave_min64(minv);        // minv is already masked
            unsigned long long tie = __ballot(minv == delta);
            int j1 = __ffsll(tie);                 // first-index tie-break
            j1 = __builtin_amdgcn_readfirstlane(j1);
            int pj1 = bcasti(p, j1 - 1);

            // prefetch next row + next u[i0] (lane pj1-1 not yet inTree)
            if (pj1 != 0) {
                c    = cb[(pj1 - 1) * DD + l];
                u_i0 = bcastf(ud, pj1 - 1);
            }

            // dual updates (reference's where()-updates, exact)
            float du = used ? delta : 0.0f;
            float di = inTree ? delta : 0.0f;
            ud += di;
            v  -= du;
            minv -= (delta - du);                  // used: -0 (BIG kept); unused: -delta

            bool isj1 = (l == (j1 - 1));
            used = used || isj1;
            minv = isj1 ? BIGF : minv;             // inject BIG for newly-used lane
            j0 = j1;
            if (pj1 == 0) break;
            inTree = inTree || (l == (pj1 - 1));
        }

        // ---- augment along way[] chain ----
        while (j0 != 0) {
            int jn = bcasti(way, j0 - 1);
            int pn = (jn == 0) ? (i + 1) : bcasti(p, jn - 1);
            if (l == (j0 - 1)) p = pn;
            j0 = jn;
        }
    }

    // ---- overwrite cost region with one-hot permutation: out[b][p-1][l] = 1 ----
    const int prow = p - 1;
    #pragma nounroll
    for (int r = 0; r < DD; ++r) {
        cb[r * DD + l] = (prow == r) ? 1.0f : 0.0f;
    }
}

extern "C" void kernel_launch(void* const* d_in, const int* in_sizes, int n_in,
                              void* d_out, int out_size, void* d_ws, size_t ws_size,
                              hipStream_t stream) {
    const float* gamma = (const float*)d_in[0];
    const float* u     = (const float*)d_in[1];
    float* out = (float*)d_out;
    const int nsamp = in_sizes[1] / (DD * DD);
    const int total4 = nsamp * DD * DD / 4;

    stage_kernel<<<dim3((total4 + 255) / 256), dim3(256), 0, stream>>>(gamma, u, out, total4);
    lap64_kernel<<<dim3((nsamp + 3) / 4), dim3(256), 0, stream>>>(out, nsamp);
}